// Round 1
// baseline (333.292 us; speedup 1.0000x reference)
//
#include <hip/hip_runtime.h>
#include <math.h>

typedef __attribute__((ext_vector_type(8))) short short8;
typedef __attribute__((ext_vector_type(4))) float f32x4;

#define BDIM 2
#define T_LEN 2048
#define CDIM 1024
#define NH 16
#define DHEAD 64
#define M_ROWS (BDIM * T_LEN)   // 4096

__device__ inline unsigned short f2bf(float f) {
    union { float f; unsigned u; } v; v.f = f;
    unsigned r = v.u + 0x7fff + ((v.u >> 16) & 1);   // round-to-nearest-even
    return (unsigned short)(r >> 16);
}

// ---------------- Kernel 1: QKV projection GEMM ----------------
// Q = x @ W^T : M=4096, N=1024, K=1024. Both operands read row-major along K.
// Output written as bf16 in [B][H][T][d] layout into workspace.
__global__ __launch_bounds__(256) void qkv_gemm(
    const float* __restrict__ x, const float* __restrict__ Wq,
    const float* __restrict__ Wk, const float* __restrict__ Wv,
    unsigned short* __restrict__ qkv)
{
    __shared__ unsigned short As[64][72];   // +8 pad: 144B row stride, 2-way-free banks
    __shared__ unsigned short Bs[64][72];
    const int z = blockIdx.z;
    const float* W = (z == 0) ? Wq : (z == 1) ? Wk : Wv;
    unsigned short* outp = qkv + (size_t)z * (M_ROWS * CDIM);
    const int m0 = blockIdx.x * 64;
    const int n0 = blockIdx.y * 64;
    const int tid = threadIdx.x;
    const int lane = tid & 63, wid = tid >> 6;
    const int wr = wid >> 1, wc = wid & 1;

    f32x4 acc[2][2] = {};
    const int sr = tid >> 2;           // staging row 0..63
    const int sc = (tid & 3) * 16;     // staging col start

    for (int k0 = 0; k0 < CDIM; k0 += 64) {
        const float* xa = x + (size_t)(m0 + sr) * CDIM + k0 + sc;
        const float* wb = W + (size_t)(n0 + sr) * CDIM + k0 + sc;
        #pragma unroll
        for (int i = 0; i < 4; ++i) {
            float4 va = *(const float4*)(xa + i * 4);
            float4 vb = *(const float4*)(wb + i * 4);
            ushort4 ua = make_ushort4(f2bf(va.x), f2bf(va.y), f2bf(va.z), f2bf(va.w));
            ushort4 ub = make_ushort4(f2bf(vb.x), f2bf(vb.y), f2bf(vb.z), f2bf(vb.w));
            *(ushort4*)&As[sr][sc + i * 4] = ua;
            *(ushort4*)&Bs[sr][sc + i * 4] = ub;
        }
        __syncthreads();
        #pragma unroll
        for (int ks = 0; ks < 2; ++ks) {
            short8 a[2], b[2];
            #pragma unroll
            for (int fm = 0; fm < 2; ++fm)
                a[fm] = *(const short8*)&As[wr * 32 + fm * 16 + (lane & 15)][ks * 32 + (lane >> 4) * 8];
            #pragma unroll
            for (int fn = 0; fn < 2; ++fn)
                b[fn] = *(const short8*)&Bs[wc * 32 + fn * 16 + (lane & 15)][ks * 32 + (lane >> 4) * 8];
            #pragma unroll
            for (int fm = 0; fm < 2; ++fm)
                #pragma unroll
                for (int fn = 0; fn < 2; ++fn)
                    acc[fm][fn] = __builtin_amdgcn_mfma_f32_16x16x32_bf16(a[fm], b[fn], acc[fm][fn], 0, 0, 0);
        }
        __syncthreads();
    }
    #pragma unroll
    for (int fm = 0; fm < 2; ++fm) {
        #pragma unroll
        for (int fn = 0; fn < 2; ++fn) {
            #pragma unroll
            for (int r = 0; r < 4; ++r) {
                int m = m0 + wr * 32 + fm * 16 + (lane >> 4) * 4 + r;
                int n = n0 + wc * 32 + fn * 16 + (lane & 15);
                int b = m >> 11, t = m & 2047;
                int h = n >> 6, dd = n & 63;
                size_t idx = ((size_t)(b * NH + h) << 17) + ((size_t)t << 6) + dd;
                outp[idx] = f2bf(acc[fm][fn][r]);
            }
        }
    }
}

// ---------------- Kernel 2: causal flash attention ----------------
// Block: 4 waves, 64 Q-rows (16/wave). KV tiles of 32 staged in LDS.
__global__ __launch_bounds__(256) void attn(
    const unsigned short* __restrict__ qkv, float* __restrict__ out)
{
    __shared__ unsigned short Ks[32][72];      // K rows (kv × d), padded
    __shared__ unsigned short Vt[64][40];      // V transposed (d × kv), padded
    __shared__ unsigned short Ps[4][16][40];   // per-wave P buffer

    const int bh = blockIdx.y;                 // b*16 + h
    const int b = bh >> 4, h = bh & 15;
    const int q0 = blockIdx.x * 64;
    const int tid = threadIdx.x;
    const int lane = tid & 63, wid = tid >> 6;

    const unsigned short* qp = qkv + (size_t)bh * (T_LEN * DHEAD);
    const unsigned short* kp = qkv + (size_t)(M_ROWS * CDIM) + (size_t)bh * (T_LEN * DHEAD);
    const unsigned short* vp = qkv + 2 * (size_t)(M_ROWS * CDIM) + (size_t)bh * (T_LEN * DHEAD);

    // Q fragments held in registers for the whole kernel
    const int qrow = q0 + wid * 16 + (lane & 15);
    short8 aq[2];
    #pragma unroll
    for (int ks = 0; ks < 2; ++ks)
        aq[ks] = *(const short8*)(qp + ((size_t)qrow << 6) + ks * 32 + (lane >> 4) * 8);

    float m_run[4], l_run[4];
    f32x4 acc_o[4] = {};
    #pragma unroll
    for (int r = 0; r < 4; ++r) { m_run[r] = -INFINITY; l_run[r] = 0.f; }

    const int rbase = (lane >> 4) * 4;
    const int ntiles = (q0 + 64) >> 5;
    const int srow = tid >> 3, scol = (tid & 7) * 8;

    for (int it = 0; it < ntiles; ++it) {
        const int kv0 = it * 32;
        __syncthreads();   // previous tile's LDS reads done before overwrite
        {
            short8 kv8 = *(const short8*)(kp + ((size_t)(kv0 + srow) << 6) + scol);
            *(short8*)&Ks[srow][scol] = kv8;
            union { short8 v; unsigned short u[8]; } vv;
            vv.v = *(const short8*)(vp + ((size_t)(kv0 + srow) << 6) + scol);
            #pragma unroll
            for (int j = 0; j < 8; ++j)
                Vt[scol + j][srow] = vv.u[j];
        }
        __syncthreads();

        // S = Q K^T  (16 x 32 per wave)
        f32x4 sacc[2] = {};
        #pragma unroll
        for (int nb = 0; nb < 2; ++nb) {
            #pragma unroll
            for (int ks = 0; ks < 2; ++ks) {
                short8 bk = *(const short8*)&Ks[nb * 16 + (lane & 15)][ks * 32 + (lane >> 4) * 8];
                sacc[nb] = __builtin_amdgcn_mfma_f32_16x16x32_bf16(aq[ks], bk, sacc[nb], 0, 0, 0);
            }
        }

        // online softmax (fp32)
        float p[2][4], corr[4];
        #pragma unroll
        for (int r = 0; r < 4; ++r) {
            int qg = q0 + wid * 16 + rbase + r;
            int k0g = kv0 + (lane & 15);
            float s0 = sacc[0][r] * 0.03125f;        // * C^-0.5 = 1/32
            float s1 = sacc[1][r] * 0.03125f;
            if (k0g > qg)      s0 = -INFINITY;
            if (k0g + 16 > qg) s1 = -INFINITY;
            float mt = fmaxf(s0, s1);
            #pragma unroll
            for (int msk = 1; msk < 16; msk <<= 1)
                mt = fmaxf(mt, __shfl_xor(mt, msk));
            float mn = fmaxf(m_run[r], mt);
            float c = expf(m_run[r] - mn);           // first tile: exp(-inf)=0
            float p0 = expf(s0 - mn);
            float p1 = expf(s1 - mn);
            float ps = p0 + p1;
            #pragma unroll
            for (int msk = 1; msk < 16; msk <<= 1)
                ps += __shfl_xor(ps, msk);
            l_run[r] = l_run[r] * c + ps;
            m_run[r] = mn;
            p[0][r] = p0; p[1][r] = p1;
            corr[r] = c;
        }

        // rescale O accumulators
        #pragma unroll
        for (int nb2 = 0; nb2 < 4; ++nb2)
            #pragma unroll
            for (int r = 0; r < 4; ++r)
                acc_o[nb2][r] *= corr[r];

        // P -> bf16 -> per-wave LDS -> A-fragment (wave-local, no barrier)
        #pragma unroll
        for (int nb = 0; nb < 2; ++nb)
            #pragma unroll
            for (int r = 0; r < 4; ++r)
                Ps[wid][rbase + r][nb * 16 + (lane & 15)] = f2bf(p[nb][r]);
        short8 pa = *(const short8*)&Ps[wid][lane & 15][(lane >> 4) * 8];

        #pragma unroll
        for (int nb2 = 0; nb2 < 4; ++nb2) {
            short8 bv = *(const short8*)&Vt[nb2 * 16 + (lane & 15)][(lane >> 4) * 8];
            acc_o[nb2] = __builtin_amdgcn_mfma_f32_16x16x32_bf16(pa, bv, acc_o[nb2], 0, 0, 0);
        }
    }

    // epilogue: out[b][t][h*64+dd], fp32
    #pragma unroll
    for (int r = 0; r < 4; ++r) {
        int t = q0 + wid * 16 + rbase + r;
        float inv = 1.0f / l_run[r];
        #pragma unroll
        for (int nb2 = 0; nb2 < 4; ++nb2) {
            int dd = nb2 * 16 + (lane & 15);
            out[(size_t)(b * T_LEN + t) * CDIM + h * DHEAD + dd] = acc_o[nb2][r] * inv;
        }
    }
}

extern "C" void kernel_launch(void* const* d_in, const int* in_sizes, int n_in,
                              void* d_out, int out_size, void* d_ws, size_t ws_size,
                              hipStream_t stream) {
    const float* x  = (const float*)d_in[0];
    const float* Wq = (const float*)d_in[1];
    const float* Wk = (const float*)d_in[2];
    const float* Wv = (const float*)d_in[3];
    unsigned short* qkv = (unsigned short*)d_ws;   // 3 * 4096*1024 bf16 = 24 MB
    float* out = (float*)d_out;

    dim3 g1(M_ROWS / 64, CDIM / 64, 3);
    qkv_gemm<<<g1, dim3(256), 0, stream>>>(x, Wq, Wk, Wv, qkv);

    dim3 g2(T_LEN / 64, BDIM * NH);
    attn<<<g2, dim3(256), 0, stream>>>(qkv, out);
}

// Round 2
// 217.374 us; speedup vs baseline: 1.5333x; 1.5333x over previous
//
#include <hip/hip_runtime.h>
#include <math.h>

typedef __attribute__((ext_vector_type(8))) short short8;
typedef __attribute__((ext_vector_type(4))) float f32x4;

#define BDIM 2
#define T_LEN 2048
#define CDIM 1024
#define NH 16
#define DHEAD 64
#define M_ROWS (BDIM * T_LEN)   // 4096

#define QB 128    // q rows per block (attn)
#define QW 32     // q rows per wave
#define KVB 64    // kv rows per tile

__device__ inline unsigned short f2bf(float f) {
    union { float f; unsigned u; } v; v.f = f;
    unsigned r = v.u + 0x7fff + ((v.u >> 16) & 1);   // round-to-nearest-even
    return (unsigned short)(r >> 16);
}

// async global->LDS, 16B per lane; LDS dest = wave-uniform base + lane*16
__device__ __forceinline__ void gload16(const unsigned short* g, unsigned short* l) {
    __builtin_amdgcn_global_load_lds(
        (const __attribute__((address_space(1))) void*)g,
        (__attribute__((address_space(3))) void*)l, 16, 0, 0);
}

// ---------------- Kernel 1: QKV projection GEMM ----------------
// Q,K written as bf16 [b][h][t][d]; V written TRANSPOSED as bf16 [b][h][d][t].
__global__ __launch_bounds__(256) void qkv_gemm(
    const float* __restrict__ x, const float* __restrict__ Wq,
    const float* __restrict__ Wk, const float* __restrict__ Wv,
    unsigned short* __restrict__ qkv)
{
    __shared__ unsigned short As[64][72];
    __shared__ unsigned short Bs[64][72];
    const int z = blockIdx.z;
    const float* W = (z == 0) ? Wq : (z == 1) ? Wk : Wv;
    const int m0 = blockIdx.x * 64;
    const int n0 = blockIdx.y * 64;
    const int tid = threadIdx.x;
    const int lane = tid & 63, wid = tid >> 6;
    const int wr = wid >> 1, wc = wid & 1;

    f32x4 acc[2][2] = {};
    const int sr = tid >> 2;
    const int sc = (tid & 3) * 16;

    for (int k0 = 0; k0 < CDIM; k0 += 64) {
        const float* xa = x + (size_t)(m0 + sr) * CDIM + k0 + sc;
        const float* wb = W + (size_t)(n0 + sr) * CDIM + k0 + sc;
        #pragma unroll
        for (int i = 0; i < 4; ++i) {
            float4 va = *(const float4*)(xa + i * 4);
            float4 vb = *(const float4*)(wb + i * 4);
            *(ushort4*)&As[sr][sc + i * 4] = make_ushort4(f2bf(va.x), f2bf(va.y), f2bf(va.z), f2bf(va.w));
            *(ushort4*)&Bs[sr][sc + i * 4] = make_ushort4(f2bf(vb.x), f2bf(vb.y), f2bf(vb.z), f2bf(vb.w));
        }
        __syncthreads();
        #pragma unroll
        for (int ks = 0; ks < 2; ++ks) {
            short8 a[2], b[2];
            #pragma unroll
            for (int fm = 0; fm < 2; ++fm)
                a[fm] = *(const short8*)&As[wr * 32 + fm * 16 + (lane & 15)][ks * 32 + (lane >> 4) * 8];
            #pragma unroll
            for (int fn = 0; fn < 2; ++fn)
                b[fn] = *(const short8*)&Bs[wc * 32 + fn * 16 + (lane & 15)][ks * 32 + (lane >> 4) * 8];
            #pragma unroll
            for (int fm = 0; fm < 2; ++fm)
                #pragma unroll
                for (int fn = 0; fn < 2; ++fn)
                    acc[fm][fn] = __builtin_amdgcn_mfma_f32_16x16x32_bf16(a[fm], b[fn], acc[fm][fn], 0, 0, 0);
        }
        __syncthreads();
    }

    if (z != 2) {
        unsigned short* outp = qkv + (size_t)z * (M_ROWS * CDIM);
        #pragma unroll
        for (int fm = 0; fm < 2; ++fm)
            #pragma unroll
            for (int fn = 0; fn < 2; ++fn)
                #pragma unroll
                for (int r = 0; r < 4; ++r) {
                    int m = m0 + wr * 32 + fm * 16 + (lane >> 4) * 4 + r;
                    int n = n0 + wc * 32 + fn * 16 + (lane & 15);
                    int b = m >> 11, t = m & 2047;
                    int h = n >> 6, dd = n & 63;
                    outp[((size_t)(b * NH + h) << 17) + ((size_t)t << 6) + dd] = f2bf(acc[fm][fn][r]);
                }
    } else {
        // transpose 64x64 tile through LDS, store V^T[bh][dd][t] coalesced
        unsigned short (*Tls)[72] = As;   // safe: loop ended with __syncthreads
        #pragma unroll
        for (int fm = 0; fm < 2; ++fm)
            #pragma unroll
            for (int fn = 0; fn < 2; ++fn) {
                ushort4 v4 = make_ushort4(f2bf(acc[fm][fn][0]), f2bf(acc[fm][fn][1]),
                                          f2bf(acc[fm][fn][2]), f2bf(acc[fm][fn][3]));
                *(ushort4*)&Tls[wc * 32 + fn * 16 + (lane & 15)][wr * 32 + fm * 16 + (lane >> 4) * 4] = v4;
            }
        __syncthreads();
        int b = m0 >> 11, h = n0 >> 6;
        unsigned short* base = qkv + 2 * (size_t)(M_ROWS * CDIM)
                             + ((size_t)(b * NH + h) << 17) + (m0 & 2047);
        #pragma unroll
        for (int rep = 0; rep < 2; ++rep) {
            int row = (tid >> 3) + rep * 32;
            int col = (tid & 7) * 8;
            *(short8*)(base + (size_t)row * T_LEN + col) = *(const short8*)&Tls[row][col];
        }
    }
}

// ---------------- Kernel 2: causal flash attention ----------------
// 4 waves, 128 q-rows/block (32/wave), KV tiles of 64, double-buffered LDS.
// K LDS [kv][64] and V^T LDS [dd][64] both XOR-swizzled: phys = lin ^ ((row&7)<<4),
// staged via global_load_lds with pre-swizzled per-lane global sources.
__global__ __launch_bounds__(256) void attn(
    const unsigned short* __restrict__ qkv, float* __restrict__ out)
{
    __shared__ __align__(16) unsigned short Klds[2][KVB * 64];
    __shared__ __align__(16) unsigned short Vlds[2][64 * KVB];
    __shared__ __align__(16) unsigned short Ps[4][QW * KVB];

    const int id = blockIdx.x;
    const int bh = (id & 7) * 4 + ((id >> 3) & 3);   // same-bh blocks share XCD
    const int bx = (T_LEN / QB - 1) - (id >> 5);      // big-q blocks first
    const int b = bh >> 4, h = bh & 15;
    const int q0 = bx * QB;
    const int tid = threadIdx.x;
    const int l = tid & 63, w = tid >> 6;
    const int li = l & 15, gi = l >> 4;

    const unsigned short* qp = qkv + (size_t)bh * (T_LEN * DHEAD);
    const unsigned short* kp = qkv + (size_t)(M_ROWS * CDIM) + (size_t)bh * (T_LEN * DHEAD);
    const unsigned short* vp = qkv + 2 * (size_t)(M_ROWS * CDIM) + (size_t)bh * (T_LEN * DHEAD); // [dd][t]

    const int q0w = q0 + w * QW;

    // Q fragments in registers
    short8 aq[2][2];
    #pragma unroll
    for (int mf = 0; mf < 2; ++mf)
        #pragma unroll
        for (int ks = 0; ks < 2; ++ks)
            aq[mf][ks] = *(const short8*)(qp + (size_t)(q0w + mf * 16 + li) * DHEAD + ks * 32 + gi * 8);

    float m_run[2][4], l_run[2][4];
    f32x4 acc_o[2][4] = {};
    #pragma unroll
    for (int mf = 0; mf < 2; ++mf)
        #pragma unroll
        for (int r = 0; r < 4; ++r) { m_run[mf][r] = -INFINITY; l_run[mf][r] = 0.f; }

    const int nt = q0 / KVB + 2;
    const int myNt = (q0w >> 6) + 1;   // tiles this wave computes

    // staging: K tile 8KB + V tile 8KB = 512+512 chunks of 16B; 2+2 instrs/wave
    auto STAGE = [&](int it, int bf) {
        const int kv0 = it * KVB;
        #pragma unroll
        for (int s = 0; s < 2; ++s) {
            int c = (w * 2 + s) * 64 + l;        // chunk index 0..511
            int row = c >> 3;                    // kv (K) or dd (V)
            int wc_ = c & 7;
            int sw = wc_ ^ (row & 7);            // pre-swizzled within-row chunk
            gload16(kp + (size_t)(kv0 + row) * DHEAD + sw * 8, &Klds[bf][(size_t)(w * 2 + s) * 512]);
            gload16(vp + (size_t)row * T_LEN + kv0 + sw * 8, &Vlds[bf][(size_t)(w * 2 + s) * 512]);
        }
    };

    STAGE(0, 0);
    asm volatile("s_waitcnt vmcnt(0)" ::: "memory");
    __syncthreads();

    for (int it = 0; it < nt; ++it) {
        const int cur = it & 1;
        if (it + 1 < nt) STAGE(it + 1, cur ^ 1);
        const int kv0 = it * KVB;

        if (it < myNt) {
            // ---- QK^T: S[32q][64kv] per wave ----
            f32x4 sacc[2][4] = {};
            #pragma unroll
            for (int nb = 0; nb < 4; ++nb)
                #pragma unroll
                for (int ks = 0; ks < 2; ++ks) {
                    int lin = (nb * 16 + li) * 128 + ks * 64 + gi * 16;
                    int phys = lin ^ ((li & 7) << 4);
                    short8 bk = *(const short8*)((const char*)&Klds[cur][0] + phys);
                    sacc[0][nb] = __builtin_amdgcn_mfma_f32_16x16x32_bf16(aq[0][ks], bk, sacc[0][nb], 0, 0, 0);
                    sacc[1][nb] = __builtin_amdgcn_mfma_f32_16x16x32_bf16(aq[1][ks], bk, sacc[1][nb], 0, 0, 0);
                }

            // ---- online softmax (fp32) + P -> swizzled per-wave LDS ----
            const bool domask = (kv0 + KVB - 1 > q0w);
            float cr[2][4];
            #pragma unroll
            for (int mf = 0; mf < 2; ++mf)
                #pragma unroll
                for (int r = 0; r < 4; ++r) {
                    int qg = q0w + mf * 16 + gi * 4 + r;
                    float sv[4];
                    #pragma unroll
                    for (int nb = 0; nb < 4; ++nb)
                        sv[nb] = sacc[mf][nb][r] * 0.03125f;   // * C^-0.5
                    if (domask) {
                        #pragma unroll
                        for (int nb = 0; nb < 4; ++nb)
                            if (kv0 + nb * 16 + li > qg) sv[nb] = -INFINITY;
                    }
                    float mt = fmaxf(fmaxf(sv[0], sv[1]), fmaxf(sv[2], sv[3]));
                    #pragma unroll
                    for (int msk = 1; msk < 16; msk <<= 1)
                        mt = fmaxf(mt, __shfl_xor(mt, msk));
                    float mo = m_run[mf][r];
                    float mn = fmaxf(mo, mt);
                    float c = __expf(mo - mn);
                    float psum = 0.f;
                    #pragma unroll
                    for (int nb = 0; nb < 4; ++nb) {
                        float p = __expf(sv[nb] - mn);
                        psum += p;
                        int lrow = mf * 16 + gi * 4 + r;
                        int lin = lrow * 128 + (nb * 16 + li) * 2;
                        int phys = lin ^ (((gi * 4 + r) & 7) << 4);
                        *(unsigned short*)((char*)&Ps[w][0] + phys) = f2bf(p);
                    }
                    #pragma unroll
                    for (int msk = 1; msk < 16; msk <<= 1)
                        psum += __shfl_xor(psum, msk);
                    l_run[mf][r] = l_run[mf][r] * c + psum;
                    m_run[mf][r] = mn;
                    cr[mf][r] = c;
                }

            // rescale O
            #pragma unroll
            for (int mf = 0; mf < 2; ++mf)
                #pragma unroll
                for (int nb2 = 0; nb2 < 4; ++nb2)
                    #pragma unroll
                    for (int r = 0; r < 4; ++r)
                        acc_o[mf][nb2][r] *= cr[mf][r];

            // ---- PV: O += P V ----
            #pragma unroll
            for (int ks = 0; ks < 2; ++ks) {
                short8 pa[2];
                #pragma unroll
                for (int mf = 0; mf < 2; ++mf) {
                    int lin = (mf * 16 + li) * 128 + ks * 64 + gi * 16;
                    int phys = lin ^ ((li & 7) << 4);
                    pa[mf] = *(const short8*)((const char*)&Ps[w][0] + phys);
                }
                #pragma unroll
                for (int nb2 = 0; nb2 < 4; ++nb2) {
                    int lin = (nb2 * 16 + li) * 128 + ks * 64 + gi * 16;
                    int phys = lin ^ ((li & 7) << 4);
                    short8 bv = *(const short8*)((const char*)&Vlds[cur][0] + phys);
                    acc_o[0][nb2] = __builtin_amdgcn_mfma_f32_16x16x32_bf16(pa[0], bv, acc_o[0][nb2], 0, 0, 0);
                    acc_o[1][nb2] = __builtin_amdgcn_mfma_f32_16x16x32_bf16(pa[1], bv, acc_o[1][nb2], 0, 0, 0);
                }
            }
        }
        asm volatile("s_waitcnt vmcnt(0)" ::: "memory");
        __syncthreads();
    }

    // ---- epilogue ----
    #pragma unroll
    for (int mf = 0; mf < 2; ++mf)
        #pragma unroll
        for (int r = 0; r < 4; ++r) {
            int t = q0w + mf * 16 + gi * 4 + r;
            float inv = 1.0f / l_run[mf][r];
            #pragma unroll
            for (int nb2 = 0; nb2 < 4; ++nb2) {
                int dd = nb2 * 16 + li;
                out[(size_t)(b * T_LEN + t) * CDIM + h * DHEAD + dd] = acc_o[mf][nb2][r] * inv;
            }
        }
}

extern "C" void kernel_launch(void* const* d_in, const int* in_sizes, int n_in,
                              void* d_out, int out_size, void* d_ws, size_t ws_size,
                              hipStream_t stream) {
    const float* x  = (const float*)d_in[0];
    const float* Wq = (const float*)d_in[1];
    const float* Wk = (const float*)d_in[2];
    const float* Wv = (const float*)d_in[3];
    unsigned short* qkv = (unsigned short*)d_ws;   // 3 * 4096*1024 bf16 = 24 MB
    float* out = (float*)d_out;

    dim3 g1(M_ROWS / 64, CDIM / 64, 3);
    qkv_gemm<<<g1, dim3(256), 0, stream>>>(x, Wq, Wk, Wv, qkv);

    attn<<<dim3((T_LEN / QB) * BDIM * NH), dim3(256), 0, stream>>>(qkv, out);
}

// Round 5
// 174.818 us; speedup vs baseline: 1.9065x; 1.2434x over previous
//
#include <hip/hip_runtime.h>
#include <math.h>

typedef __attribute__((ext_vector_type(8))) short short8;
typedef __attribute__((ext_vector_type(4))) float f32x4;

#define BDIM 2
#define T_LEN 2048
#define CDIM 1024
#define NH 16
#define DHEAD 64
#define M_ROWS (BDIM * T_LEN)            // 4096
#define NX (M_ROWS * CDIM)               // 4194304
#define NW (CDIM * CDIM)                 // 1048576

#define QB 128    // q rows per block (attn)
#define QW 32     // q rows per wave
#define KVB 64    // kv rows per tile

__device__ inline unsigned short f2bf(float f) {
    union { float f; unsigned u; } v; v.f = f;
    unsigned r = v.u + 0x7fff + ((v.u >> 16) & 1);   // RNE
    return (unsigned short)(r >> 16);
}

__device__ __forceinline__ void gload16(const unsigned short* g, unsigned short* l) {
    __builtin_amdgcn_global_load_lds(
        (const __attribute__((address_space(1))) void*)g,
        (__attribute__((address_space(3))) void*)l, 16, 0, 0);
}

// ---------------- Kernel 0: fp32 -> bf16 convert (x, Wq, Wk, Wv) ----------------
__global__ __launch_bounds__(256) void conv_bf16(
    const float* __restrict__ x, const float* __restrict__ wq,
    const float* __restrict__ wk, const float* __restrict__ wv,
    unsigned short* __restrict__ dst)
{
    int id = blockIdx.x * 256 + threadIdx.x;        // 16B-out chunk id
    const float* s;
    if (id < NX / 8) s = x + (size_t)id * 8;
    else {
        int r = id - NX / 8;
        int wsel = r >> 17;                          // NW/8 = 131072 = 2^17
        int off = r & 131071;
        const float* w = (wsel == 0) ? wq : (wsel == 1) ? wk : wv;
        s = w + (size_t)off * 8;
    }
    float4 a = ((const float4*)s)[0];
    float4 b = ((const float4*)s)[1];
    union { unsigned short u[8]; short8 v; } o;
    o.u[0] = f2bf(a.x); o.u[1] = f2bf(a.y); o.u[2] = f2bf(a.z); o.u[3] = f2bf(a.w);
    o.u[4] = f2bf(b.x); o.u[5] = f2bf(b.y); o.u[6] = f2bf(b.z); o.u[7] = f2bf(b.w);
    *(short8*)(dst + (size_t)id * 8) = o.v;
}

// ---------------- Kernel 1: QKV GEMM (round-2 structure, bf16 inputs) ----------------
// Identical to the PASSED round-2 qkv_gemm except staging loads bf16 directly
// (no fp32->bf16 conversion in the loop). Same tiles, same MFMA, same epilogues.
__global__ __launch_bounds__(256) void qkv_gemm_b(
    const unsigned short* __restrict__ xb, const unsigned short* __restrict__ wball,
    unsigned short* __restrict__ qkv)
{
    __shared__ unsigned short As[64][72];   // +8 pad, 144B row stride (16B-aligned rows)
    __shared__ unsigned short Bs[64][72];
    const int z = blockIdx.z;
    const unsigned short* wsrc = wball + (size_t)z * NW;
    const int m0 = blockIdx.x * 64;
    const int n0 = blockIdx.y * 64;
    const int tid = threadIdx.x;
    const int lane = tid & 63, wid = tid >> 6;
    const int wr = wid >> 1, wc = wid & 1;

    f32x4 acc[2][2] = {};
    const int sr = tid >> 2;           // staging row 0..63
    const int sc = (tid & 3) * 16;     // staging col start

    for (int k0 = 0; k0 < CDIM; k0 += 64) {
        const unsigned short* xa = xb + (size_t)(m0 + sr) * CDIM + k0 + sc;
        const unsigned short* wp = wsrc + (size_t)(n0 + sr) * CDIM + k0 + sc;
        *(short8*)&As[sr][sc]     = *(const short8*)xa;
        *(short8*)&As[sr][sc + 8] = *(const short8*)(xa + 8);
        *(short8*)&Bs[sr][sc]     = *(const short8*)wp;
        *(short8*)&Bs[sr][sc + 8] = *(const short8*)(wp + 8);
        __syncthreads();
        #pragma unroll
        for (int ks = 0; ks < 2; ++ks) {
            short8 a[2], b[2];
            #pragma unroll
            for (int fm = 0; fm < 2; ++fm)
                a[fm] = *(const short8*)&As[wr * 32 + fm * 16 + (lane & 15)][ks * 32 + (lane >> 4) * 8];
            #pragma unroll
            for (int fn = 0; fn < 2; ++fn)
                b[fn] = *(const short8*)&Bs[wc * 32 + fn * 16 + (lane & 15)][ks * 32 + (lane >> 4) * 8];
            #pragma unroll
            for (int fm = 0; fm < 2; ++fm)
                #pragma unroll
                for (int fn = 0; fn < 2; ++fn)
                    acc[fm][fn] = __builtin_amdgcn_mfma_f32_16x16x32_bf16(a[fm], b[fn], acc[fm][fn], 0, 0, 0);
        }
        __syncthreads();
    }
    if (z != 2) {
        unsigned short* outp = qkv + (size_t)z * NX;
        #pragma unroll
        for (int fm = 0; fm < 2; ++fm)
            #pragma unroll
            for (int fn = 0; fn < 2; ++fn)
                #pragma unroll
                for (int r = 0; r < 4; ++r) {
                    int m = m0 + wr * 32 + fm * 16 + (lane >> 4) * 4 + r;
                    int n = n0 + wc * 32 + fn * 16 + (lane & 15);
                    int b = m >> 11, t = m & 2047;
                    int h = n >> 6, dd = n & 63;
                    outp[((size_t)(b * NH + h) << 17) + ((size_t)t << 6) + dd] = f2bf(acc[fm][fn][r]);
                }
    } else {
        unsigned short (*Tls)[72] = As;
        #pragma unroll
        for (int fm = 0; fm < 2; ++fm)
            #pragma unroll
            for (int fn = 0; fn < 2; ++fn) {
                ushort4 v4 = make_ushort4(f2bf(acc[fm][fn][0]), f2bf(acc[fm][fn][1]),
                                          f2bf(acc[fm][fn][2]), f2bf(acc[fm][fn][3]));
                *(ushort4*)&Tls[wc * 32 + fn * 16 + (lane & 15)][wr * 32 + fm * 16 + (lane >> 4) * 4] = v4;
            }
        __syncthreads();
        int b = m0 >> 11, h = n0 >> 6;
        unsigned short* base = qkv + 2 * (size_t)NX + ((size_t)(b * NH + h) << 17) + (m0 & 2047);
        #pragma unroll
        for (int rep = 0; rep < 2; ++rep) {
            int row = (tid >> 3) + rep * 32;
            int col = (tid & 7) * 8;
            *(short8*)(base + (size_t)row * T_LEN + col) = *(const short8*)&Tls[row][col];
        }
    }
}

// ---------------- Kernel 2: causal flash attention (round-2 verbatim + setprio) ----------------
__global__ __launch_bounds__(256) void attn(
    const unsigned short* __restrict__ qkv, float* __restrict__ out)
{
    __shared__ __align__(16) unsigned short Klds[2][KVB * 64];
    __shared__ __align__(16) unsigned short Vlds[2][64 * KVB];
    __shared__ __align__(16) unsigned short Ps[4][QW * KVB];

    const int id = blockIdx.x;
    const int bh = (id & 7) * 4 + ((id >> 3) & 3);   // same-bh blocks share XCD
    const int bx = (T_LEN / QB - 1) - (id >> 5);      // big-q blocks first
    const int b = bh >> 4, h = bh & 15;
    const int q0 = bx * QB;
    const int tid = threadIdx.x;
    const int l = tid & 63, w = tid >> 6;
    const int li = l & 15, gi = l >> 4;

    const unsigned short* qp = qkv + (size_t)bh * (T_LEN * DHEAD);
    const unsigned short* kp = qkv + (size_t)NX + (size_t)bh * (T_LEN * DHEAD);
    const unsigned short* vp = qkv + 2 * (size_t)NX + (size_t)bh * (T_LEN * DHEAD); // [dd][t]

    const int q0w = q0 + w * QW;

    short8 aq[2][2];
    #pragma unroll
    for (int mf = 0; mf < 2; ++mf)
        #pragma unroll
        for (int ks = 0; ks < 2; ++ks)
            aq[mf][ks] = *(const short8*)(qp + (size_t)(q0w + mf * 16 + li) * DHEAD + ks * 32 + gi * 8);

    float m_run[2][4], l_run[2][4];
    f32x4 acc_o[2][4] = {};
    #pragma unroll
    for (int mf = 0; mf < 2; ++mf)
        #pragma unroll
        for (int r = 0; r < 4; ++r) { m_run[mf][r] = -INFINITY; l_run[mf][r] = 0.f; }

    const int nt = q0 / KVB + 2;
    const int myNt = (q0w >> 6) + 1;

    auto STAGE = [&](int it, int bf) {
        const int kv0 = it * KVB;
        #pragma unroll
        for (int s = 0; s < 2; ++s) {
            int c = (w * 2 + s) * 64 + l;
            int row = c >> 3, wc_ = c & 7;
            int sw = wc_ ^ (row & 7);
            gload16(kp + (size_t)(kv0 + row) * DHEAD + sw * 8, &Klds[bf][(w * 2 + s) * 512]);
            gload16(vp + (size_t)row * T_LEN + kv0 + sw * 8, &Vlds[bf][(w * 2 + s) * 512]);
        }
    };

    STAGE(0, 0);
    asm volatile("s_waitcnt vmcnt(0)" ::: "memory");
    __syncthreads();

    for (int it = 0; it < nt; ++it) {
        const int cur = it & 1;
        if (it + 1 < nt) STAGE(it + 1, cur ^ 1);
        const int kv0 = it * KVB;

        if (it < myNt) {
            f32x4 sacc[2][4] = {};
            __builtin_amdgcn_s_setprio(1);
            #pragma unroll
            for (int nb = 0; nb < 4; ++nb)
                #pragma unroll
                for (int ks = 0; ks < 2; ++ks) {
                    int lin = (nb * 16 + li) * 128 + ks * 64 + gi * 16;
                    int phys = lin ^ ((li & 7) << 4);
                    short8 bk = *(const short8*)((const char*)&Klds[cur][0] + phys);
                    sacc[0][nb] = __builtin_amdgcn_mfma_f32_16x16x32_bf16(aq[0][ks], bk, sacc[0][nb], 0, 0, 0);
                    sacc[1][nb] = __builtin_amdgcn_mfma_f32_16x16x32_bf16(aq[1][ks], bk, sacc[1][nb], 0, 0, 0);
                }
            __builtin_amdgcn_s_setprio(0);

            const bool domask = (kv0 + KVB - 1 > q0w);
            float cr[2][4];
            #pragma unroll
            for (int mf = 0; mf < 2; ++mf)
                #pragma unroll
                for (int r = 0; r < 4; ++r) {
                    int qg = q0w + mf * 16 + gi * 4 + r;
                    float sv[4];
                    #pragma unroll
                    for (int nb = 0; nb < 4; ++nb)
                        sv[nb] = sacc[mf][nb][r] * 0.03125f;   // * C^-0.5
                    if (domask) {
                        #pragma unroll
                        for (int nb = 0; nb < 4; ++nb)
                            if (kv0 + nb * 16 + li > qg) sv[nb] = -INFINITY;
                    }
                    float mt = fmaxf(fmaxf(sv[0], sv[1]), fmaxf(sv[2], sv[3]));
                    #pragma unroll
                    for (int msk = 1; msk < 16; msk <<= 1)
                        mt = fmaxf(mt, __shfl_xor(mt, msk));
                    float mo = m_run[mf][r];
                    float mn = fmaxf(mo, mt);
                    float c = __expf(mo - mn);
                    float psum = 0.f;
                    #pragma unroll
                    for (int nb = 0; nb < 4; ++nb) {
                        float p = __expf(sv[nb] - mn);
                        psum += p;
                        int lrow = mf * 16 + gi * 4 + r;
                        int lin = lrow * 128 + (nb * 16 + li) * 2;
                        int phys = lin ^ (((gi * 4 + r) & 7) << 4);
                        *(unsigned short*)((char*)&Ps[w][0] + phys) = f2bf(p);
                    }
                    #pragma unroll
                    for (int msk = 1; msk < 16; msk <<= 1)
                        psum += __shfl_xor(psum, msk);
                    l_run[mf][r] = l_run[mf][r] * c + psum;
                    m_run[mf][r] = mn;
                    cr[mf][r] = c;
                }

            #pragma unroll
            for (int mf = 0; mf < 2; ++mf)
                #pragma unroll
                for (int nb2 = 0; nb2 < 4; ++nb2)
                    #pragma unroll
                    for (int r = 0; r < 4; ++r)
                        acc_o[mf][nb2][r] *= cr[mf][r];

            __builtin_amdgcn_s_setprio(1);
            #pragma unroll
            for (int ks = 0; ks < 2; ++ks) {
                short8 pa[2];
                #pragma unroll
                for (int mf = 0; mf < 2; ++mf) {
                    int lin = (mf * 16 + li) * 128 + ks * 64 + gi * 16;
                    int phys = lin ^ ((li & 7) << 4);
                    pa[mf] = *(const short8*)((const char*)&Ps[w][0] + phys);
                }
                #pragma unroll
                for (int nb2 = 0; nb2 < 4; ++nb2) {
                    int lin = (nb2 * 16 + li) * 128 + ks * 64 + gi * 16;
                    int phys = lin ^ ((li & 7) << 4);
                    short8 bv = *(const short8*)((const char*)&Vlds[cur][0] + phys);
                    acc_o[0][nb2] = __builtin_amdgcn_mfma_f32_16x16x32_bf16(pa[0], bv, acc_o[0][nb2], 0, 0, 0);
                    acc_o[1][nb2] = __builtin_amdgcn_mfma_f32_16x16x32_bf16(pa[1], bv, acc_o[1][nb2], 0, 0, 0);
                }
            }
            __builtin_amdgcn_s_setprio(0);
        }
        asm volatile("s_waitcnt vmcnt(0)" ::: "memory");
        __syncthreads();
    }

    #pragma unroll
    for (int mf = 0; mf < 2; ++mf)
        #pragma unroll
        for (int r = 0; r < 4; ++r) {
            int t = q0w + mf * 16 + gi * 4 + r;
            float inv = 1.0f / l_run[mf][r];
            #pragma unroll
            for (int nb2 = 0; nb2 < 4; ++nb2) {
                int dd = nb2 * 16 + li;
                out[(size_t)(b * T_LEN + t) * CDIM + h * DHEAD + dd] = acc_o[mf][nb2][r] * inv;
            }
        }
}

extern "C" void kernel_launch(void* const* d_in, const int* in_sizes, int n_in,
                              void* d_out, int out_size, void* d_ws, size_t ws_size,
                              hipStream_t stream) {
    const float* x  = (const float*)d_in[0];
    const float* Wq = (const float*)d_in[1];
    const float* Wk = (const float*)d_in[2];
    const float* Wv = (const float*)d_in[3];
    float* out = (float*)d_out;

    // bf16 scratch (14 MB) lives in d_out (16 MB): written by conv, read only by
    // qkv_gemm_b, then fully overwritten by attn's fp32 output. qkv in d_ws (24 MB).
    unsigned short* xb = (unsigned short*)d_out;
    unsigned short* wb = xb + NX;
    unsigned short* qkv = (unsigned short*)d_ws;

    conv_bf16<<<dim3((NX / 8 + 3 * NW / 8) / 256), dim3(256), 0, stream>>>(x, Wq, Wk, Wv, xb);
    qkv_gemm_b<<<dim3(M_ROWS / 64, CDIM / 64, 3), dim3(256), 0, stream>>>(xb, wb, qkv);
    attn<<<dim3((T_LEN / QB) * BDIM * NH), dim3(256), 0, stream>>>(qkv, out);
}

// Round 6
// 127.598 us; speedup vs baseline: 2.6121x; 1.3701x over previous
//
#include <hip/hip_runtime.h>
#include <math.h>

typedef __attribute__((ext_vector_type(8))) short short8;
typedef __attribute__((ext_vector_type(4))) float f32x4;
typedef __attribute__((ext_vector_type(16))) float f32x16;

#define BDIM 2
#define T_LEN 2048
#define CDIM 1024
#define NH 16
#define DHEAD 64
#define M_ROWS (BDIM * T_LEN)            // 4096
#define NX (M_ROWS * CDIM)               // 4194304
#define NW (CDIM * CDIM)                 // 1048576

#define KVB 64

__device__ inline unsigned short f2bf(float f) {
    union { float f; unsigned u; } v; v.f = f;
    unsigned r = v.u + 0x7fff + ((v.u >> 16) & 1);   // RNE
    return (unsigned short)(r >> 16);
}

__device__ __forceinline__ void gload16(const unsigned short* g, unsigned short* l) {
    __builtin_amdgcn_global_load_lds(
        (const __attribute__((address_space(1))) void*)g,
        (__attribute__((address_space(3))) void*)l, 16, 0, 0);
}

// ---------------- Kernel 0: fp32 -> bf16 convert (x, Wq, Wk, Wv) ----------------
__global__ __launch_bounds__(256) void conv_bf16(
    const float* __restrict__ x, const float* __restrict__ wq,
    const float* __restrict__ wk, const float* __restrict__ wv,
    unsigned short* __restrict__ dst)
{
    int id = blockIdx.x * 256 + threadIdx.x;        // 16B-out chunk id
    const float* s;
    if (id < NX / 8) s = x + (size_t)id * 8;
    else {
        int r = id - NX / 8;
        int wsel = r >> 17;                          // NW/8 = 131072 = 2^17
        int off = r & 131071;
        const float* w = (wsel == 0) ? wq : (wsel == 1) ? wk : wv;
        s = w + (size_t)off * 8;
    }
    float4 a = ((const float4*)s)[0];
    float4 b = ((const float4*)s)[1];
    union { unsigned short u[8]; short8 v; } o;
    o.u[0] = f2bf(a.x); o.u[1] = f2bf(a.y); o.u[2] = f2bf(a.z); o.u[3] = f2bf(a.w);
    o.u[4] = f2bf(b.x); o.u[5] = f2bf(b.y); o.u[6] = f2bf(b.z); o.u[7] = f2bf(b.w);
    *(short8*)(dst + (size_t)id * 8) = o.v;
}

// ---------------- Kernel 1: bf16 QKV GEMM, 128x128 tile, BK=64 ----------------
// Q,K -> [b][h][t][d]; V -> transposed [b][h][d][t].
// FIX vs rounds 3/4: V^T epilogue t-offset uses (m0 & 2047), not raw m0.
__global__ __launch_bounds__(256) void qkv_gemm_f(
    const unsigned short* __restrict__ xb, const unsigned short* __restrict__ wb,
    unsigned short* __restrict__ qkv)
{
    __shared__ unsigned short sh[17408];             // A:0..8191, B:8192..16383; epilogue T buf
    unsigned short* A = sh;
    unsigned short* Bt = sh + 8192;
    const int z = blockIdx.z;
    const int m0 = blockIdx.x * 128;
    const int n0 = blockIdx.y * 128;
    const int tid = threadIdx.x;
    const int l = tid & 63, w = tid >> 6;
    const int li = l & 15, g4 = l >> 4;
    const int wr = w >> 1, wc = w & 1;

    const unsigned short* wsrc = wb + (size_t)z * NW;
    f32x4 acc[4][4] = {};

    for (int k0 = 0; k0 < CDIM; k0 += 64) {
        __syncthreads();
        #pragma unroll
        for (int s = 0; s < 4; ++s) {
            int c = w * 256 + s * 64 + l;            // chunk 0..1023
            int row = c >> 3, wcol = c & 7;
            int sw = wcol ^ (row & 7);
            gload16(xb + (size_t)(m0 + row) * CDIM + k0 + sw * 8, A + (w * 256 + s * 64) * 8);
            gload16(wsrc + (size_t)(n0 + row) * CDIM + k0 + sw * 8, Bt + (w * 256 + s * 64) * 8);
        }
        asm volatile("s_waitcnt vmcnt(0)" ::: "memory");
        __syncthreads();
        __builtin_amdgcn_s_setprio(1);
        #pragma unroll
        for (int ks = 0; ks < 2; ++ks) {
            short8 af[4], bf[4];
            #pragma unroll
            for (int fm = 0; fm < 4; ++fm) {
                int row = wr * 64 + fm * 16 + li;
                int lin = row * 128 + ks * 64 + g4 * 16;
                af[fm] = *(const short8*)((const char*)A + (lin ^ ((row & 7) << 4)));
            }
            #pragma unroll
            for (int fn = 0; fn < 4; ++fn) {
                int row = wc * 64 + fn * 16 + li;
                int lin = row * 128 + ks * 64 + g4 * 16;
                bf[fn] = *(const short8*)((const char*)Bt + (lin ^ ((row & 7) << 4)));
            }
            #pragma unroll
            for (int fm = 0; fm < 4; ++fm)
                #pragma unroll
                for (int fn = 0; fn < 4; ++fn)
                    acc[fm][fn] = __builtin_amdgcn_mfma_f32_16x16x32_bf16(af[fm], bf[fn], acc[fm][fn], 0, 0, 0);
        }
        __builtin_amdgcn_s_setprio(0);
    }
    __syncthreads();

    if (z != 2) {
        unsigned short* outp = qkv + (size_t)z * NX;
        #pragma unroll
        for (int fm = 0; fm < 4; ++fm)
            #pragma unroll
            for (int fn = 0; fn < 4; ++fn)
                #pragma unroll
                for (int r = 0; r < 4; ++r) {
                    int m = m0 + wr * 64 + fm * 16 + g4 * 4 + r;
                    int n = n0 + wc * 64 + fn * 16 + li;
                    int b = m >> 11, t = m & 2047;
                    int h = n >> 6, dd = n & 63;
                    outp[((size_t)(b * NH + h) << 17) + ((size_t)t << 6) + dd] = f2bf(acc[fm][fn][r]);
                }
    } else {
        // transpose through LDS -> V^T[bh][dd][t]
        unsigned short (*T)[136] = (unsigned short(*)[136])sh;
        #pragma unroll
        for (int fm = 0; fm < 4; ++fm)
            #pragma unroll
            for (int fn = 0; fn < 4; ++fn)
                #pragma unroll
                for (int r = 0; r < 4; ++r) {
                    int ml = wr * 64 + fm * 16 + g4 * 4 + r;
                    int nl = wc * 64 + fn * 16 + li;
                    T[nl][ml] = f2bf(acc[fm][fn][r]);
                }
        __syncthreads();
        int b = m0 >> 11;
        int t0 = m0 & 2047;                           // THE FIX
        unsigned short* vt = qkv + 2 * (size_t)NX;
        #pragma unroll
        for (int s = 0; s < 8; ++s) {
            int row = tid >> 1;                       // n_local 0..127
            int col = ((tid & 1) * 8 + s) * 8;        // m_local
            int ng = n0 + row;
            int h = ng >> 6, dd = ng & 63;
            *(short8*)(vt + ((size_t)(b * NH + h) * 64 + dd) * T_LEN + t0 + col)
                = *(const short8*)&T[row][col];
        }
    }
}

// ---------------- Kernel 2: causal flash attention (swapped QK^T, 32x32 MFMA) ----------------
// 4 waves, 128 q-rows/block (32/wave). Lane owns q-column (l&31): softmax in registers.
__global__ __launch_bounds__(256) void attn(
    const unsigned short* __restrict__ qkv, float* __restrict__ out)
{
    __shared__ __align__(16) unsigned short Klds[2][KVB * 64];
    __shared__ __align__(16) unsigned short Vlds[2][64 * KVB];

    const int id = blockIdx.x;
    const int xcd = id & 7, j = id >> 3;
    const int bh = xcd * 4 + (j & 3);
    const int bx = 15 - (j >> 2);                     // big-q blocks first
    const int b = bh >> 4, h = bh & 15;
    const int q0 = bx * 128;
    const int tid = threadIdx.x;
    const int l = tid & 63, w = tid >> 6;
    const int q31 = l & 31, hi = l >> 5;

    const unsigned short* qp = qkv + (size_t)bh * (T_LEN * DHEAD);
    const unsigned short* kp = qkv + (size_t)NX + (size_t)bh * (T_LEN * DHEAD);
    const unsigned short* vp = qkv + 2 * (size_t)NX + (size_t)bh * (T_LEN * DHEAD); // [dd][t]

    const int q0w = q0 + w * 32;
    const int qg = q0w + q31;

    // Q as B-operand fragments: B[k][q] = Q[q][k]; lane holds k = ks*16 + hi*8 + j
    short8 aq[4];
    #pragma unroll
    for (int ks = 0; ks < 4; ++ks)
        aq[ks] = *(const short8*)(qp + (size_t)qg * DHEAD + ks * 16 + hi * 8);

    float m_run = -INFINITY, l_run = 0.f;
    f32x16 acc_o[2] = {};                             // O^T[dd][q]

    const int nt = q0 / KVB + 2;
    const int myNt = q0w / KVB + 1;
    const float SCL = 0.04508422f;                    // (1/32) * log2(e)

    auto STAGE = [&](int it, int bf) {
        const int kv0 = it * KVB;
        #pragma unroll
        for (int s = 0; s < 2; ++s) {
            int c = (w * 2 + s) * 64 + l;
            int row = c >> 3, wc_ = c & 7;
            int sw = wc_ ^ (row & 7);
            gload16(kp + (size_t)(kv0 + row) * DHEAD + sw * 8, &Klds[bf][(w * 2 + s) * 512]);
            gload16(vp + (size_t)row * T_LEN + kv0 + sw * 8, &Vlds[bf][(w * 2 + s) * 512]);
        }
    };

    STAGE(0, 0);
    asm volatile("s_waitcnt vmcnt(0)" ::: "memory");
    __syncthreads();

    for (int it = 0; it < nt; ++it) {
        const int cur = it & 1;
        if (it + 1 < nt) STAGE(it + 1, cur ^ 1);
        const int kv0 = it * KVB;

        if (it < myNt) {
            // ---- S^T = K Q^T : lane owns q-col q31, 32 of 64 kv rows (split with l^32) ----
            f32x16 sacc[2] = {};
            __builtin_amdgcn_s_setprio(1);
            #pragma unroll
            for (int ks = 0; ks < 4; ++ks) {
                #pragma unroll
                for (int nb = 0; nb < 2; ++nb) {
                    int row = 32 * nb + q31;
                    int lin = row * 128 + ks * 32 + hi * 16;
                    short8 ak = *(const short8*)((const char*)&Klds[cur][0] + (lin ^ ((l & 7) << 4)));
                    sacc[nb] = __builtin_amdgcn_mfma_f32_32x32x16_bf16(ak, aq[ks], sacc[nb], 0, 0, 0);
                }
            }
            __builtin_amdgcn_s_setprio(0);

            // ---- in-register online softmax (exp2 domain) ----
            const bool domask = (kv0 + KVB - 1 > q0w);
            float mloc = -INFINITY;
            #pragma unroll
            for (int nb = 0; nb < 2; ++nb)
                #pragma unroll
                for (int r = 0; r < 16; ++r) {
                    float s = sacc[nb][r] * SCL;
                    if (domask) {
                        int kvg = kv0 + 32 * nb + (r & 3) + 8 * (r >> 2) + 4 * hi;
                        if (kvg > qg) s = -INFINITY;
                    }
                    sacc[nb][r] = s;
                    mloc = fmaxf(mloc, s);
                }
            mloc = fmaxf(mloc, __shfl_xor(mloc, 32));
            float mn = fmaxf(m_run, mloc);
            float c = exp2f(m_run - mn);
            float psum = 0.f;
            #pragma unroll
            for (int nb = 0; nb < 2; ++nb)
                #pragma unroll
                for (int r = 0; r < 16; ++r) {
                    float p = exp2f(sacc[nb][r] - mn);
                    sacc[nb][r] = p;
                    psum += p;
                }
            psum += __shfl_xor(psum, 32);
            l_run = l_run * c + psum;
            m_run = mn;
            #pragma unroll
            for (int nb2 = 0; nb2 < 2; ++nb2)
                #pragma unroll
                for (int r = 0; r < 16; ++r)
                    acc_o[nb2][r] *= c;

            // ---- pack P^T B-fragments: cvt_pk pairs + cross-half exchange ----
            unsigned dw[16], xw[16];
            #pragma unroll
            for (int u = 0; u < 16; ++u) {
                float lo = sacc[u >> 3][(2 * u) & 15];
                float hif = sacc[u >> 3][((2 * u) & 15) + 1];
                asm("v_cvt_pk_bf16_f32 %0, %1, %2" : "=v"(dw[u]) : "v"(lo), "v"(hif));
            }
            #pragma unroll
            for (int u = 0; u < 16; ++u)
                xw[u] = (unsigned)__shfl_xor((int)dw[u], 32);

            // ---- O^T += V^T P^T ----
            __builtin_amdgcn_s_setprio(1);
            #pragma unroll
            for (int ks = 0; ks < 4; ++ks) {
                union { unsigned u[4]; short8 v; } pb;
                pb.u[0] = hi ? xw[4 * ks + 2] : dw[4 * ks];
                pb.u[1] = hi ? xw[4 * ks + 3] : dw[4 * ks + 1];
                pb.u[2] = hi ? dw[4 * ks + 2] : xw[4 * ks];
                pb.u[3] = hi ? dw[4 * ks + 3] : xw[4 * ks + 1];
                #pragma unroll
                for (int nb2 = 0; nb2 < 2; ++nb2) {
                    int row = 32 * nb2 + q31;
                    int lin = row * 128 + ks * 32 + hi * 16;
                    short8 av = *(const short8*)((const char*)&Vlds[cur][0] + (lin ^ ((l & 7) << 4)));
                    acc_o[nb2] = __builtin_amdgcn_mfma_f32_32x32x16_bf16(av, pb.v, acc_o[nb2], 0, 0, 0);
                }
            }
            __builtin_amdgcn_s_setprio(0);
        }
        asm volatile("s_waitcnt vmcnt(0)" ::: "memory");
        __syncthreads();
    }

    // ---- epilogue: out[b][t][h*64+dd] = O^T[dd][q]/l ----
    float inv = 1.0f / l_run;
    float* ob = out + ((size_t)(b * T_LEN + qg)) * CDIM + h * DHEAD;
    #pragma unroll
    for (int nb2 = 0; nb2 < 2; ++nb2)
        #pragma unroll
        for (int r = 0; r < 16; ++r) {
            int dd = 32 * nb2 + (r & 3) + 8 * (r >> 2) + 4 * hi;
            ob[dd] = acc_o[nb2][r] * inv;
        }
}

extern "C" void kernel_launch(void* const* d_in, const int* in_sizes, int n_in,
                              void* d_out, int out_size, void* d_ws, size_t ws_size,
                              hipStream_t stream) {
    const float* x  = (const float*)d_in[0];
    const float* Wq = (const float*)d_in[1];
    const float* Wk = (const float*)d_in[2];
    const float* Wv = (const float*)d_in[3];
    float* out = (float*)d_out;

    // bf16 scratch (14 MB) in d_out (16 MB): written by conv, read only by
    // qkv_gemm_f, then fully overwritten by attn's fp32 output. qkv in d_ws (24 MB).
    unsigned short* xb = (unsigned short*)d_out;
    unsigned short* wb = xb + NX;
    unsigned short* qkv = (unsigned short*)d_ws;

    conv_bf16<<<dim3((NX / 8 + 3 * NW / 8) / 256), dim3(256), 0, stream>>>(x, Wq, Wk, Wv, xb);
    qkv_gemm_f<<<dim3(M_ROWS / 128, CDIM / 128, 3), dim3(256), 0, stream>>>(xb, wb, qkv);
    attn<<<dim3(512), dim3(256), 0, stream>>>(qkv, out);
}

// Round 7
// 113.838 us; speedup vs baseline: 2.9278x; 1.1209x over previous
//
#include <hip/hip_runtime.h>
#include <math.h>

typedef __attribute__((ext_vector_type(8))) short short8;
typedef __attribute__((ext_vector_type(4))) float f32x4;
typedef __attribute__((ext_vector_type(16))) float f32x16;

#define BDIM 2
#define T_LEN 2048
#define CDIM 1024
#define NH 16
#define DHEAD 64
#define M_ROWS (BDIM * T_LEN)            // 4096
#define NX (M_ROWS * CDIM)               // 4194304
#define NW (CDIM * CDIM)                 // 1048576

#define KVB 64
#define QSCL 0.045084220f                // C^-0.5 * log2(e), folded into Wq

__device__ inline unsigned short f2bf(float f) {
    union { float f; unsigned u; } v; v.f = f;
    unsigned r = v.u + 0x7fff + ((v.u >> 16) & 1);   // RNE
    return (unsigned short)(r >> 16);
}

__device__ __forceinline__ void gload16(const unsigned short* g, unsigned short* l) {
    __builtin_amdgcn_global_load_lds(
        (const __attribute__((address_space(1))) void*)g,
        (__attribute__((address_space(3))) void*)l, 16, 0, 0);
}

// ---------------- Kernel 0: fp32 -> bf16 convert (x, Wq*QSCL, Wk, Wv) ----------------
__global__ __launch_bounds__(256) void conv_bf16(
    const float* __restrict__ x, const float* __restrict__ wq,
    const float* __restrict__ wk, const float* __restrict__ wv,
    unsigned short* __restrict__ dst)
{
    int id = blockIdx.x * 256 + threadIdx.x;        // 16B-out chunk id
    const float* s;
    float scl = 1.0f;
    if (id < NX / 8) s = x + (size_t)id * 8;
    else {
        int r = id - NX / 8;
        int wsel = r >> 17;                          // NW/8 = 131072 = 2^17
        int off = r & 131071;
        const float* w = (wsel == 0) ? wq : (wsel == 1) ? wk : wv;
        if (wsel == 0) scl = QSCL;                   // pre-scale Q via Wq
        s = w + (size_t)off * 8;
    }
    float4 a = ((const float4*)s)[0];
    float4 b = ((const float4*)s)[1];
    union { unsigned short u[8]; short8 v; } o;
    o.u[0] = f2bf(a.x * scl); o.u[1] = f2bf(a.y * scl); o.u[2] = f2bf(a.z * scl); o.u[3] = f2bf(a.w * scl);
    o.u[4] = f2bf(b.x * scl); o.u[5] = f2bf(b.y * scl); o.u[6] = f2bf(b.z * scl); o.u[7] = f2bf(b.w * scl);
    *(short8*)(dst + (size_t)id * 8) = o.v;
}

// ---------------- Kernel 1: bf16 QKV GEMM, 128x128 tile, BK=64 ----------------
// Q,K -> [b][h][t][d]; V -> transposed [b][h][d][t].
__global__ __launch_bounds__(256) void qkv_gemm_f(
    const unsigned short* __restrict__ xb, const unsigned short* __restrict__ wb,
    unsigned short* __restrict__ qkv)
{
    __shared__ unsigned short sh[17408];             // A:0..8191, B:8192..16383; epilogue T buf
    unsigned short* A = sh;
    unsigned short* Bt = sh + 8192;
    const int z = blockIdx.z;
    const int m0 = blockIdx.x * 128;
    const int n0 = blockIdx.y * 128;
    const int tid = threadIdx.x;
    const int l = tid & 63, w = tid >> 6;
    const int li = l & 15, g4 = l >> 4;
    const int wr = w >> 1, wc = w & 1;

    const unsigned short* wsrc = wb + (size_t)z * NW;
    f32x4 acc[4][4] = {};

    for (int k0 = 0; k0 < CDIM; k0 += 64) {
        __syncthreads();
        #pragma unroll
        for (int s = 0; s < 4; ++s) {
            int c = w * 256 + s * 64 + l;            // chunk 0..1023
            int row = c >> 3, wcol = c & 7;
            int sw = wcol ^ (row & 7);
            gload16(xb + (size_t)(m0 + row) * CDIM + k0 + sw * 8, A + (w * 256 + s * 64) * 8);
            gload16(wsrc + (size_t)(n0 + row) * CDIM + k0 + sw * 8, Bt + (w * 256 + s * 64) * 8);
        }
        asm volatile("s_waitcnt vmcnt(0)" ::: "memory");
        __syncthreads();
        __builtin_amdgcn_s_setprio(1);
        #pragma unroll
        for (int ks = 0; ks < 2; ++ks) {
            short8 af[4], bf[4];
            #pragma unroll
            for (int fm = 0; fm < 4; ++fm) {
                int row = wr * 64 + fm * 16 + li;
                int lin = row * 128 + ks * 64 + g4 * 16;
                af[fm] = *(const short8*)((const char*)A + (lin ^ ((row & 7) << 4)));
            }
            #pragma unroll
            for (int fn = 0; fn < 4; ++fn) {
                int row = wc * 64 + fn * 16 + li;
                int lin = row * 128 + ks * 64 + g4 * 16;
                bf[fn] = *(const short8*)((const char*)Bt + (lin ^ ((row & 7) << 4)));
            }
            #pragma unroll
            for (int fm = 0; fm < 4; ++fm)
                #pragma unroll
                for (int fn = 0; fn < 4; ++fn)
                    acc[fm][fn] = __builtin_amdgcn_mfma_f32_16x16x32_bf16(af[fm], bf[fn], acc[fm][fn], 0, 0, 0);
        }
        __builtin_amdgcn_s_setprio(0);
    }
    __syncthreads();

    if (z != 2) {
        unsigned short* outp = qkv + (size_t)z * NX;
        #pragma unroll
        for (int fm = 0; fm < 4; ++fm)
            #pragma unroll
            for (int fn = 0; fn < 4; ++fn)
                #pragma unroll
                for (int r = 0; r < 4; ++r) {
                    int m = m0 + wr * 64 + fm * 16 + g4 * 4 + r;
                    int n = n0 + wc * 64 + fn * 16 + li;
                    int b = m >> 11, t = m & 2047;
                    int h = n >> 6, dd = n & 63;
                    outp[((size_t)(b * NH + h) << 17) + ((size_t)t << 6) + dd] = f2bf(acc[fm][fn][r]);
                }
    } else {
        // transpose through LDS -> V^T[bh][dd][t]
        unsigned short (*T)[136] = (unsigned short(*)[136])sh;
        #pragma unroll
        for (int fm = 0; fm < 4; ++fm)
            #pragma unroll
            for (int fn = 0; fn < 4; ++fn)
                #pragma unroll
                for (int r = 0; r < 4; ++r) {
                    int ml = wr * 64 + fm * 16 + g4 * 4 + r;
                    int nl = wc * 64 + fn * 16 + li;
                    T[nl][ml] = f2bf(acc[fm][fn][r]);
                }
        __syncthreads();
        int b = m0 >> 11;
        int t0 = m0 & 2047;
        unsigned short* vt = qkv + 2 * (size_t)NX;
        #pragma unroll
        for (int s = 0; s < 8; ++s) {
            int row = tid >> 1;                       // n_local 0..127
            int col = ((tid & 1) * 8 + s) * 8;        // m_local
            int ng = n0 + row;
            int h = ng >> 6, dd = ng & 63;
            *(short8*)(vt + ((size_t)(b * NH + h) * 64 + dd) * T_LEN + t0 + col)
                = *(const short8*)&T[row][col];
        }
    }
}

// ---------------- Kernel 2: causal flash attention (swapped QK^T, 32x32 MFMA) ----------------
__global__ __launch_bounds__(256) void attn(
    const unsigned short* __restrict__ qkv, float* __restrict__ out)
{
    __shared__ __align__(16) unsigned short Klds[2][KVB * 64];
    __shared__ __align__(16) unsigned short Vlds[2][64 * KVB];

    const int id = blockIdx.x;
    // CU-balanced pairing: blocks c and c+256 land on the same CU (all 512
    // co-resident); bx(c) + bx(c+256) == 15 -> constant work per CU.
    const int half = id >> 8;                         // 0: bx 15..8, 1: bx 0..7
    const int rr_ = id & 255;
    const int tI = rr_ >> 5;                          // 0..7
    const int bx = half ? tI : (15 - tI);
    const int rb = rr_ & 31;
    const int bh = (rb & 7) * 4 + (rb >> 3);          // XCD spread
    const int b = bh >> 4, h = bh & 15;
    const int q0 = bx * 128;
    const int tid = threadIdx.x;
    const int l = tid & 63, w = tid >> 6;
    const int q31 = l & 31, hi = l >> 5;

    const unsigned short* qp = qkv + (size_t)bh * (T_LEN * DHEAD);
    const unsigned short* kp = qkv + (size_t)NX + (size_t)bh * (T_LEN * DHEAD);
    const unsigned short* vp = qkv + 2 * (size_t)NX + (size_t)bh * (T_LEN * DHEAD); // [dd][t]

    const int q0w = q0 + w * 32;
    const int qg = q0w + q31;

    // Q as B-operand fragments: B[k][q] = Q[q][k] (Q pre-scaled by QSCL via Wq)
    short8 aq[4];
    #pragma unroll
    for (int ks = 0; ks < 4; ++ks)
        aq[ks] = *(const short8*)(qp + (size_t)qg * DHEAD + ks * 16 + hi * 8);

    float m_run = -INFINITY, l_run = 0.f;
    f32x16 acc_o[2] = {};                             // O^T[dd][q]

    const int nt = q0 / KVB + 2;
    const int myNt = q0w / KVB + 1;

    auto STAGE = [&](int it, int bf) {
        const int kv0 = it * KVB;
        #pragma unroll
        for (int s = 0; s < 2; ++s) {
            int c = (w * 2 + s) * 64 + l;
            int row = c >> 3, wc_ = c & 7;
            int sw = wc_ ^ (row & 7);
            gload16(kp + (size_t)(kv0 + row) * DHEAD + sw * 8, &Klds[bf][(w * 2 + s) * 512]);
            gload16(vp + (size_t)row * T_LEN + kv0 + sw * 8, &Vlds[bf][(w * 2 + s) * 512]);
        }
    };

    STAGE(0, 0);
    asm volatile("s_waitcnt vmcnt(0)" ::: "memory");
    __syncthreads();

    for (int it = 0; it < nt; ++it) {
        const int cur = it & 1;
        if (it + 1 < nt) STAGE(it + 1, cur ^ 1);
        const int kv0 = it * KVB;

        if (it < myNt) {
            // ---- S^T = K Q^T : lane owns q-col q31, 32 of 64 kv rows ----
            f32x16 sacc[2] = {};
            __builtin_amdgcn_s_setprio(1);
            #pragma unroll
            for (int ks = 0; ks < 4; ++ks) {
                #pragma unroll
                for (int nb = 0; nb < 2; ++nb) {
                    int row = 32 * nb + q31;
                    int lin = row * 128 + ks * 32 + hi * 16;
                    short8 ak = *(const short8*)((const char*)&Klds[cur][0] + (lin ^ ((l & 7) << 4)));
                    sacc[nb] = __builtin_amdgcn_mfma_f32_32x32x16_bf16(ak, aq[ks], sacc[nb], 0, 0, 0);
                }
            }
            __builtin_amdgcn_s_setprio(0);

            // ---- online softmax (exp2 domain, S pre-scaled) ----
            const bool domask = (kv0 + KVB - 1 > q0w);
            if (domask) {
                #pragma unroll
                for (int nb = 0; nb < 2; ++nb)
                    #pragma unroll
                    for (int r = 0; r < 16; ++r) {
                        int kvg = kv0 + 32 * nb + (r & 3) + 8 * (r >> 2) + 4 * hi;
                        if (kvg > qg) sacc[nb][r] = -INFINITY;
                    }
            }
            // tree max (depth 5 + 1 shfl)
            float m16[16];
            #pragma unroll
            for (int r = 0; r < 16; ++r) m16[r] = fmaxf(sacc[0][r], sacc[1][r]);
            #pragma unroll
            for (int st = 8; st >= 1; st >>= 1)
                #pragma unroll
                for (int r2 = 0; r2 < 8; ++r2)
                    if (r2 < st) m16[r2] = fmaxf(m16[r2], m16[r2 + st]);
            float mloc = fmaxf(m16[0], __shfl_xor(m16[0], 32));

            // defer-max: skip rescale unless max grew past threshold
            bool upd = mloc > m_run + 8.0f;
            if (__any(upd)) {
                float mn = fmaxf(m_run, mloc);
                float c = exp2f(m_run - mn);
                l_run *= c;
                #pragma unroll
                for (int nb2 = 0; nb2 < 2; ++nb2)
                    #pragma unroll
                    for (int r = 0; r < 16; ++r)
                        acc_o[nb2][r] *= c;
                m_run = mn;
            }
            // exp2 + tree sum
            float ps[16];
            #pragma unroll
            for (int r = 0; r < 16; ++r) {
                float p0 = exp2f(sacc[0][r] - m_run);
                float p1 = exp2f(sacc[1][r] - m_run);
                sacc[0][r] = p0; sacc[1][r] = p1;
                ps[r] = p0 + p1;
            }
            #pragma unroll
            for (int st = 8; st >= 1; st >>= 1)
                #pragma unroll
                for (int r2 = 0; r2 < 8; ++r2)
                    if (r2 < st) ps[r2] += ps[r2 + st];
            l_run += ps[0] + __shfl_xor(ps[0], 32);

            // ---- pack P^T B-fragments: cvt_pk pairs + cross-half exchange ----
            unsigned dw[16], xw[16];
            #pragma unroll
            for (int u = 0; u < 16; ++u) {
                float lo = sacc[u >> 3][(2 * u) & 15];
                float hif = sacc[u >> 3][((2 * u) & 15) + 1];
                asm("v_cvt_pk_bf16_f32 %0, %1, %2" : "=v"(dw[u]) : "v"(lo), "v"(hif));
            }
            #pragma unroll
            for (int u = 0; u < 16; ++u)
                xw[u] = (unsigned)__shfl_xor((int)dw[u], 32);

            // ---- O^T += V^T P^T ----
            __builtin_amdgcn_s_setprio(1);
            #pragma unroll
            for (int ks = 0; ks < 4; ++ks) {
                union { unsigned u[4]; short8 v; } pb;
                pb.u[0] = hi ? xw[4 * ks + 2] : dw[4 * ks];
                pb.u[1] = hi ? xw[4 * ks + 3] : dw[4 * ks + 1];
                pb.u[2] = hi ? dw[4 * ks + 2] : xw[4 * ks];
                pb.u[3] = hi ? dw[4 * ks + 3] : xw[4 * ks + 1];
                #pragma unroll
                for (int nb2 = 0; nb2 < 2; ++nb2) {
                    int row = 32 * nb2 + q31;
                    int lin = row * 128 + ks * 32 + hi * 16;
                    short8 av = *(const short8*)((const char*)&Vlds[cur][0] + (lin ^ ((l & 7) << 4)));
                    acc_o[nb2] = __builtin_amdgcn_mfma_f32_32x32x16_bf16(av, pb.v, acc_o[nb2], 0, 0, 0);
                }
            }
            __builtin_amdgcn_s_setprio(0);
        }
        asm volatile("s_waitcnt vmcnt(0)" ::: "memory");
        __syncthreads();
    }

    // ---- epilogue: out[b][t][h*64+dd] = O^T[dd][q]/l ----
    float inv = 1.0f / l_run;
    float* ob = out + ((size_t)(b * T_LEN + qg)) * CDIM + h * DHEAD;
    #pragma unroll
    for (int nb2 = 0; nb2 < 2; ++nb2)
        #pragma unroll
        for (int r = 0; r < 16; ++r) {
            int dd = 32 * nb2 + (r & 3) + 8 * (r >> 2) + 4 * hi;
            ob[dd] = acc_o[nb2][r] * inv;
        }
}

extern "C" void kernel_launch(void* const* d_in, const int* in_sizes, int n_in,
                              void* d_out, int out_size, void* d_ws, size_t ws_size,
                              hipStream_t stream) {
    const float* x  = (const float*)d_in[0];
    const float* Wq = (const float*)d_in[1];
    const float* Wk = (const float*)d_in[2];
    const float* Wv = (const float*)d_in[3];
    float* out = (float*)d_out;

    // bf16 scratch (14 MB) in d_out (16 MB): written by conv, read only by
    // qkv_gemm_f, then fully overwritten by attn's fp32 output. qkv in d_ws (24 MB).
    unsigned short* xb = (unsigned short*)d_out;
    unsigned short* wb = xb + NX;
    unsigned short* qkv = (unsigned short*)d_ws;

    conv_bf16<<<dim3((NX / 8 + 3 * NW / 8) / 256), dim3(256), 0, stream>>>(x, Wq, Wk, Wv, xb);
    qkv_gemm_f<<<dim3(M_ROWS / 128, CDIM / 128, 3), dim3(256), 0, stream>>>(xb, wb, qkv);
    attn<<<dim3(512), dim3(256), 0, stream>>>(qkv, out);
}

// Round 8
// 107.287 us; speedup vs baseline: 3.1065x; 1.0611x over previous
//
#include <hip/hip_runtime.h>
#include <math.h>

typedef __attribute__((ext_vector_type(8))) short short8;
typedef __attribute__((ext_vector_type(4))) float f32x4;
typedef __attribute__((ext_vector_type(16))) float f32x16;

#define BDIM 2
#define T_LEN 2048
#define CDIM 1024
#define NH 16
#define DHEAD 64
#define M_ROWS (BDIM * T_LEN)            // 4096
#define NX (M_ROWS * CDIM)               // 4194304
#define NW (CDIM * CDIM)                 // 1048576

#define KVB 64
#define QSCL 0.045084220f                // C^-0.5 * log2(e), folded into Wq

__device__ inline unsigned short f2bf(float f) {
    union { float f; unsigned u; } v; v.f = f;
    unsigned r = v.u + 0x7fff + ((v.u >> 16) & 1);   // RNE
    return (unsigned short)(r >> 16);
}

__device__ __forceinline__ void gload16(const unsigned short* g, unsigned short* l) {
    __builtin_amdgcn_global_load_lds(
        (const __attribute__((address_space(1))) void*)g,
        (__attribute__((address_space(3))) void*)l, 16, 0, 0);
}

// ---------------- Kernel 0: fp32 -> bf16 convert (x, Wq*QSCL, Wk, Wv) ----------------
__global__ __launch_bounds__(256) void conv_bf16(
    const float* __restrict__ x, const float* __restrict__ wq,
    const float* __restrict__ wk, const float* __restrict__ wv,
    unsigned short* __restrict__ dst)
{
    int id = blockIdx.x * 256 + threadIdx.x;        // 16B-out chunk id
    const float* s;
    float scl = 1.0f;
    if (id < NX / 8) s = x + (size_t)id * 8;
    else {
        int r = id - NX / 8;
        int wsel = r >> 17;                          // NW/8 = 131072 = 2^17
        int off = r & 131071;
        const float* w = (wsel == 0) ? wq : (wsel == 1) ? wk : wv;
        if (wsel == 0) scl = QSCL;                   // pre-scale Q via Wq
        s = w + (size_t)off * 8;
    }
    float4 a = ((const float4*)s)[0];
    float4 b = ((const float4*)s)[1];
    union { unsigned short u[8]; short8 v; } o;
    o.u[0] = f2bf(a.x * scl); o.u[1] = f2bf(a.y * scl); o.u[2] = f2bf(a.z * scl); o.u[3] = f2bf(a.w * scl);
    o.u[4] = f2bf(b.x * scl); o.u[5] = f2bf(b.y * scl); o.u[6] = f2bf(b.z * scl); o.u[7] = f2bf(b.w * scl);
    *(short8*)(dst + (size_t)id * 8) = o.v;
}

// ---------------- Kernel 1: bf16 QKV GEMM, 128x128 tile, BK=64 ----------------
// Q,K -> [b][h][t][d]; V -> transposed [b][h][d][t].
__global__ __launch_bounds__(256) void qkv_gemm_f(
    const unsigned short* __restrict__ xb, const unsigned short* __restrict__ wb,
    unsigned short* __restrict__ qkv)
{
    __shared__ unsigned short sh[17408];
    unsigned short* A = sh;
    unsigned short* Bt = sh + 8192;
    const int z = blockIdx.z;
    const int m0 = blockIdx.x * 128;
    const int n0 = blockIdx.y * 128;
    const int tid = threadIdx.x;
    const int l = tid & 63, w = tid >> 6;
    const int li = l & 15, g4 = l >> 4;
    const int wr = w >> 1, wc = w & 1;

    const unsigned short* wsrc = wb + (size_t)z * NW;
    f32x4 acc[4][4] = {};

    for (int k0 = 0; k0 < CDIM; k0 += 64) {
        __syncthreads();
        #pragma unroll
        for (int s = 0; s < 4; ++s) {
            int c = w * 256 + s * 64 + l;
            int row = c >> 3, wcol = c & 7;
            int sw = wcol ^ (row & 7);
            gload16(xb + (size_t)(m0 + row) * CDIM + k0 + sw * 8, A + (w * 256 + s * 64) * 8);
            gload16(wsrc + (size_t)(n0 + row) * CDIM + k0 + sw * 8, Bt + (w * 256 + s * 64) * 8);
        }
        asm volatile("s_waitcnt vmcnt(0)" ::: "memory");
        __syncthreads();
        __builtin_amdgcn_s_setprio(1);
        #pragma unroll
        for (int ks = 0; ks < 2; ++ks) {
            short8 af[4], bf[4];
            #pragma unroll
            for (int fm = 0; fm < 4; ++fm) {
                int row = wr * 64 + fm * 16 + li;
                int lin = row * 128 + ks * 64 + g4 * 16;
                af[fm] = *(const short8*)((const char*)A + (lin ^ ((row & 7) << 4)));
            }
            #pragma unroll
            for (int fn = 0; fn < 4; ++fn) {
                int row = wc * 64 + fn * 16 + li;
                int lin = row * 128 + ks * 64 + g4 * 16;
                bf[fn] = *(const short8*)((const char*)Bt + (lin ^ ((row & 7) << 4)));
            }
            #pragma unroll
            for (int fm = 0; fm < 4; ++fm)
                #pragma unroll
                for (int fn = 0; fn < 4; ++fn)
                    acc[fm][fn] = __builtin_amdgcn_mfma_f32_16x16x32_bf16(af[fm], bf[fn], acc[fm][fn], 0, 0, 0);
        }
        __builtin_amdgcn_s_setprio(0);
    }
    __syncthreads();

    if (z != 2) {
        unsigned short* outp = qkv + (size_t)z * NX;
        #pragma unroll
        for (int fm = 0; fm < 4; ++fm)
            #pragma unroll
            for (int fn = 0; fn < 4; ++fn)
                #pragma unroll
                for (int r = 0; r < 4; ++r) {
                    int m = m0 + wr * 64 + fm * 16 + g4 * 4 + r;
                    int n = n0 + wc * 64 + fn * 16 + li;
                    int b = m >> 11, t = m & 2047;
                    int h = n >> 6, dd = n & 63;
                    outp[((size_t)(b * NH + h) << 17) + ((size_t)t << 6) + dd] = f2bf(acc[fm][fn][r]);
                }
    } else {
        unsigned short (*T)[136] = (unsigned short(*)[136])sh;
        #pragma unroll
        for (int fm = 0; fm < 4; ++fm)
            #pragma unroll
            for (int fn = 0; fn < 4; ++fn)
                #pragma unroll
                for (int r = 0; r < 4; ++r) {
                    int ml = wr * 64 + fm * 16 + g4 * 4 + r;
                    int nl = wc * 64 + fn * 16 + li;
                    T[nl][ml] = f2bf(acc[fm][fn][r]);
                }
        __syncthreads();
        int b = m0 >> 11;
        int t0 = m0 & 2047;
        unsigned short* vt = qkv + 2 * (size_t)NX;
        #pragma unroll
        for (int s = 0; s < 8; ++s) {
            int row = tid >> 1;
            int col = ((tid & 1) * 8 + s) * 8;
            int ng = n0 + row;
            int h = ng >> 6, dd = ng & 63;
            *(short8*)(vt + ((size_t)(b * NH + h) * 64 + dd) * T_LEN + t0 + col)
                = *(const short8*)&T[row][col];
        }
    }
}

// ---------------- Kernel 2: causal flash attention, 8-wave in-block KV-split ----------------
// Waves 0-3: q-chunks over kv-tiles [0,bx+1); waves 4-7: same q-chunks over [bx+1,2bx+2).
// Final merge of (m,l,O) via LDS. Swapped QK^T (32x32 MFMA), softmax in registers,
// permlane32_swap for the P^T cross-half exchange.
__global__ __launch_bounds__(512, 4) void attn(
    const unsigned short* __restrict__ qkv, float* __restrict__ out)
{
    // [half][dbuf][K=0/V=1][4096 shorts = 8KB]  -> 64 KB total
    __shared__ __align__(16) unsigned short KV[2][2][2][4096];

    const int id = blockIdx.x;
    const int rb = id & 31;
    const int bh = (rb & 7) * 4 + (rb >> 3);          // XCD spread, same-bh same XCD
    const int bx = 15 - (id >> 5);                    // long blocks first (LPT)
    const int b = bh >> 4, h = bh & 15;
    const int q0 = bx * 128;
    const int tid = threadIdx.x;
    const int l = tid & 63, w = tid >> 6;             // w: 0..7
    const int hf = w >> 2, chunk = w & 3;
    const int q31 = l & 31, hi = l >> 5;

    const unsigned short* qp = qkv + (size_t)bh * (T_LEN * DHEAD);
    const unsigned short* kp = qkv + (size_t)NX + (size_t)bh * (T_LEN * DHEAD);
    const unsigned short* vp = qkv + 2 * (size_t)NX + (size_t)bh * (T_LEN * DHEAD); // [dd][t]

    const int q0w = q0 + chunk * 32;
    const int qg = q0w + q31;

    // Q as B-operand fragments (pre-scaled by QSCL via Wq)
    short8 aq[4];
    #pragma unroll
    for (int ks = 0; ks < 4; ++ks)
        aq[ks] = *(const short8*)(qp + (size_t)qg * DHEAD + ks * 16 + hi * 8);

    float m_run = -INFINITY, l_run = 0.f;
    f32x16 acc_o[2] = {};

    const int nIt = bx + 1;                           // iterations per half
    const int Tbase = hf * nIt;
    const int myNt = 2 * bx + (chunk >> 1) + 1;       // causal tile limit for this chunk

    auto STAGE = [&](int tile, int bf) {
        const int kv0 = tile * KVB;
        #pragma unroll
        for (int s = 0; s < 2; ++s) {
            int c = (chunk * 2 + s) * 64 + l;
            int row = c >> 3, wc_ = c & 7;
            int sw = wc_ ^ (row & 7);
            gload16(kp + (size_t)(kv0 + row) * DHEAD + sw * 8, &KV[hf][bf][0][(chunk * 2 + s) * 512]);
            gload16(vp + (size_t)row * T_LEN + kv0 + sw * 8, &KV[hf][bf][1][(chunk * 2 + s) * 512]);
        }
    };

    STAGE(Tbase, 0);
    asm volatile("s_waitcnt vmcnt(0)" ::: "memory");
    __syncthreads();

    for (int i = 0; i < nIt; ++i) {
        const int cur = i & 1;
        if (i + 1 < nIt) STAGE(Tbase + i + 1, cur ^ 1);
        const int Ti = Tbase + i;
        const int kv0 = Ti * KVB;

        if (Ti < myNt) {
            const char* Kbase = (const char*)&KV[hf][cur][0][0];
            const char* Vbase = (const char*)&KV[hf][cur][1][0];

            // ---- S^T = K Q^T ----
            f32x16 sacc[2] = {};
            __builtin_amdgcn_s_setprio(1);
            #pragma unroll
            for (int ks = 0; ks < 4; ++ks) {
                #pragma unroll
                for (int nb = 0; nb < 2; ++nb) {
                    int row = 32 * nb + q31;
                    int lin = row * 128 + ks * 32 + hi * 16;
                    short8 ak = *(const short8*)(Kbase + (lin ^ ((l & 7) << 4)));
                    sacc[nb] = __builtin_amdgcn_mfma_f32_32x32x16_bf16(ak, aq[ks], sacc[nb], 0, 0, 0);
                }
            }
            __builtin_amdgcn_s_setprio(0);

            // ---- online softmax (exp2 domain) ----
            const bool domask = (kv0 + KVB - 1 > q0w);
            if (domask) {
                #pragma unroll
                for (int nb = 0; nb < 2; ++nb)
                    #pragma unroll
                    for (int r = 0; r < 16; ++r) {
                        int kvg = kv0 + 32 * nb + (r & 3) + 8 * (r >> 2) + 4 * hi;
                        if (kvg > qg) sacc[nb][r] = -INFINITY;
                    }
            }
            float m16[16];
            #pragma unroll
            for (int r = 0; r < 16; ++r) m16[r] = fmaxf(sacc[0][r], sacc[1][r]);
            #pragma unroll
            for (int st = 8; st >= 1; st >>= 1)
                #pragma unroll
                for (int r2 = 0; r2 < 8; ++r2)
                    if (r2 < st) m16[r2] = fmaxf(m16[r2], m16[r2 + st]);
            float mloc = fmaxf(m16[0], __shfl_xor(m16[0], 32));

            bool upd = mloc > m_run + 8.0f;           // defer-max
            if (__any(upd)) {
                float mn = fmaxf(m_run, mloc);
                float c = exp2f(m_run - mn);
                l_run *= c;
                #pragma unroll
                for (int nb2 = 0; nb2 < 2; ++nb2)
                    #pragma unroll
                    for (int r = 0; r < 16; ++r)
                        acc_o[nb2][r] *= c;
                m_run = mn;
            }
            float ps[16];
            #pragma unroll
            for (int r = 0; r < 16; ++r) {
                float p0 = exp2f(sacc[0][r] - m_run);
                float p1 = exp2f(sacc[1][r] - m_run);
                sacc[0][r] = p0; sacc[1][r] = p1;
                ps[r] = p0 + p1;
            }
            #pragma unroll
            for (int st = 8; st >= 1; st >>= 1)
                #pragma unroll
                for (int r2 = 0; r2 < 8; ++r2)
                    if (r2 < st) ps[r2] += ps[r2 + st];
            l_run += ps[0] + __shfl_xor(ps[0], 32);

            // ---- pack P^T: cvt_pk pairs, then permlane32_swap cross-half ----
            unsigned dw[16];
            #pragma unroll
            for (int u = 0; u < 16; ++u) {
                float lo = sacc[u >> 3][(2 * u) & 15];
                float hif = sacc[u >> 3][((2 * u) & 15) + 1];
                asm("v_cvt_pk_bf16_f32 %0, %1, %2" : "=v"(dw[u]) : "v"(lo), "v"(hif));
            }

            // ---- O^T += V^T P^T ----
            __builtin_amdgcn_s_setprio(1);
            #pragma unroll
            for (int ks = 0; ks < 4; ++ks) {
                unsigned a0 = dw[4 * ks],     b0 = dw[4 * ks + 2];
                unsigned a1 = dw[4 * ks + 1], b1 = dw[4 * ks + 3];
                // a' = {a.lo, b.lo} (pb0), b' = {a.hi, b.hi} (pb2)
                asm("v_permlane32_swap_b32 %0, %1" : "+v"(a0), "+v"(b0));
                asm("v_permlane32_swap_b32 %0, %1" : "+v"(a1), "+v"(b1));
                union { unsigned u[4]; short8 v; } pb;
                pb.u[0] = a0; pb.u[1] = a1; pb.u[2] = b0; pb.u[3] = b1;
                #pragma unroll
                for (int nb2 = 0; nb2 < 2; ++nb2) {
                    int row = 32 * nb2 + q31;
                    int lin = row * 128 + ks * 32 + hi * 16;
                    short8 av = *(const short8*)(Vbase + (lin ^ ((l & 7) << 4)));
                    acc_o[nb2] = __builtin_amdgcn_mfma_f32_32x32x16_bf16(av, pb.v, acc_o[nb2], 0, 0, 0);
                }
            }
            __builtin_amdgcn_s_setprio(0);
        }
        asm volatile("s_waitcnt vmcnt(0)" ::: "memory");
        __syncthreads();
    }

    // ---- merge halves via LDS: half B publishes, half A combines + writes out ----
    float* MB = (float*)&KV[0][0][0][0];              // 64KB >= 4*64*34*4B
    float* slot = MB + (chunk * 64 + l) * 34;
    if (hf) {
        #pragma unroll
        for (int nb2 = 0; nb2 < 2; ++nb2)
            #pragma unroll
            for (int r = 0; r < 16; ++r) slot[nb2 * 16 + r] = acc_o[nb2][r];
        slot[32] = m_run; slot[33] = l_run;
    }
    __syncthreads();
    if (!hf) {
        float mB = slot[32], lB = slot[33];
        float m = fmaxf(m_run, mB);
        float cA = exp2f(m_run - m), cB = exp2f(mB - m);
        float inv = 1.0f / (l_run * cA + lB * cB);
        float* ob = out + ((size_t)(b * T_LEN + qg)) * CDIM + h * DHEAD;
        #pragma unroll
        for (int nb2 = 0; nb2 < 2; ++nb2)
            #pragma unroll
            for (int r = 0; r < 16; ++r) {
                int dd = 32 * nb2 + (r & 3) + 8 * (r >> 2) + 4 * hi;
                ob[dd] = (acc_o[nb2][r] * cA + slot[nb2 * 16 + r] * cB) * inv;
            }
    }
}

extern "C" void kernel_launch(void* const* d_in, const int* in_sizes, int n_in,
                              void* d_out, int out_size, void* d_ws, size_t ws_size,
                              hipStream_t stream) {
    const float* x  = (const float*)d_in[0];
    const float* Wq = (const float*)d_in[1];
    const float* Wk = (const float*)d_in[2];
    const float* Wv = (const float*)d_in[3];
    float* out = (float*)d_out;

    unsigned short* xb = (unsigned short*)d_out;      // bf16 scratch in d_out (overwritten by attn)
    unsigned short* wb = xb + NX;
    unsigned short* qkv = (unsigned short*)d_ws;

    conv_bf16<<<dim3((NX / 8 + 3 * NW / 8) / 256), dim3(256), 0, stream>>>(x, Wq, Wk, Wv, xb);
    qkv_gemm_f<<<dim3(M_ROWS / 128, CDIM / 128, 3), dim3(256), 0, stream>>>(xb, wb, qkv);
    attn<<<dim3(512), dim3(512), 0, stream>>>(qkv, out);
}